// Round 4
// baseline (164.783 us; speedup 1.0000x reference)
//
#include <hip/hip_runtime.h>
#include <hip/hip_bf16.h>

#define BATCH   16384
#define NSTEPS  100
#define DT_     0.01f
#define SQRTDT  0.1f
#define SIGMA0_ 0.5f

typedef _Float16  f16x2  __attribute__((ext_vector_type(2)));
typedef _Float16  f16x4  __attribute__((ext_vector_type(4)));
typedef _Float16  f16x8  __attribute__((ext_vector_type(8)));
typedef __fp16    h16x2  __attribute__((ext_vector_type(2)));
typedef float     f32x4  __attribute__((ext_vector_type(4)));

typedef const __attribute__((address_space(1))) void* gas_ptr;
typedef __attribute__((address_space(3))) void*       las_ptr;

__global__ void zero_out_kernel(float* out) { if (threadIdx.x == 0) out[0] = 0.0f; }

static __device__ __forceinline__ f16x4 pk4(const f32x4& d) {
    union { h16x2 h[2]; f16x4 v; } c;
    c.h[0] = __builtin_amdgcn_cvt_pkrtz(d[0], d[1]);
    c.h[1] = __builtin_amdgcn_cvt_pkrtz(d[2], d[3]);
    return c.v;
}

// R4: t-dependent h1 prefix (A1*t + C1, 16 pk_fma/step) hoisted into a
// one-time LDS table (100 steps x 4 q4 x 16 f16x2 = 25.6 KB; bit-identical
// pk-fma arithmetic, accumulated t). Table reads are q4-uniform ds_read_b128
// broadcasts, prefetched one step ahead into ping-pong registers (2x
// unrolled loop) so LDS latency stays off the y-recurrence. L3 biases moved
// into the MFMA C-input (Pz seeded with {zb3*SQRTDT, qb30}); t removed from
// the loop. h1: 48 -> 32 VALU/step; epilogue: -4.
__launch_bounds__(256, 1)
__global__ void deepbsde_kernel(
    const float* __restrict__ y0,  const float* __restrict__ Y0,
    const float* __restrict__ zW1, const float* __restrict__ zb1,
    const float* __restrict__ zW2, const float* __restrict__ zb2,
    const float* __restrict__ zW3, const float* __restrict__ zb3,
    const float* __restrict__ qW1, const float* __restrict__ qb1,
    const float* __restrict__ qW2, const float* __restrict__ qb2,
    const float* __restrict__ qW3, const float* __restrict__ qb3,
    const float* __restrict__ dW,  const float* __restrict__ dZ,
    float* __restrict__ out)
{
    __shared__ __align__(16) char ring[4][8][384];        // [wave][slot][16 paths * 24B]
    __shared__ __align__(16) _Float16 tbl[NSTEPS * 128];  // [step][q4][16 f16x2]

    const int tid  = threadIdx.x;
    const int lane = tid & 63;
    const int w    = tid >> 6;
    const int ln15 = lane & 15, q4 = lane >> 4;
    const int gw   = (blockIdx.x << 2) + w;
    const int pbase = gw << 4;

    auto fill = [&](int i) {
        if (lane < 24) {
            const char* g = (lane < 12)
                ? (const char*)dW + ((size_t)i * BATCH + pbase) * 12 + (size_t)lane * 16
                : (const char*)dZ + ((size_t)i * BATCH + pbase) * 12 + (size_t)(lane - 12) * 16;
            __builtin_amdgcn_global_load_lds((gas_ptr)g, (las_ptr)&ring[w][i & 7][0],
                                             16, 0, 0);
        }
    };
    fill(0); fill(1); fill(2); fill(3);   // start HBM traffic before prologue math

    // ---- one-time t-table: entry (i,q4e,mlp,m) = A1[m]*t_i + C1[m] (pk f16),
    //      t_i accumulated exactly as the old loop did. 64 of 256 threads
    //      produce one entry per step. ----
    {
        float tt = 0.0f;
        for (int i = 0; i < NSTEPS; ++i) {
            int r = (tid - (i << 6)) & 255;
            if (r < 64) {
                int q4e = r >> 4, mlp = (r >> 3) & 1, m = r & 7;
                const float* Wp = mlp ? qW1 : zW1;
                const float* bp = mlp ? qb1 : zb1;
                int i0 = 2*m, i1 = 2*m + 1;
                int k0 = 32*(i0 >> 3) + 8*q4e + (i0 & 7);
                int k1 = 32*(i1 >> 3) + 8*q4e + (i1 & 7);
                _Float16 th = (_Float16)tt;
                f16x2 A = {(_Float16)Wp[k0], (_Float16)Wp[k1]};
                f16x2 C = {(_Float16)bp[k0], (_Float16)bp[k1]};
                f16x2 tv = {th, th};
                f16x2 v = A*tv + C;                     // v_pk_fma_f16, as before
                int idx = (i*4 + q4e)*16 + mlp*8 + m;
                *(f16x2*)&tbl[idx << 1] = v;
            }
            tt += DT_;
        }
    }

    // ---- layer-1 y-coefficients (B1 = W1 row 1) as f16x2 pairs ----
    f16x2 B1z[8], B1q[8];
#pragma unroll
    for (int m = 0; m < 8; ++m) {
        int i0 = 2*m, i1 = 2*m + 1;
        int k0 = 32*(i0 >> 3) + 8*q4 + (i0 & 7);
        int k1 = 32*(i1 >> 3) + 8*q4 + (i1 & 7);
        B1z[m] = (f16x2){(_Float16)zW1[64 + k0], (_Float16)zW1[64 + k1]};
        B1q[m] = (f16x2){(_Float16)qW1[64 + k0], (_Float16)qW1[64 + k1]};
    }

    // ---- resident W2^T A-frags in f16: A[n=16tN+ln15][k=32f+8q4+j] ----
    f16x8 AfZ[4][2], AfQ[4][2];
#pragma unroll
    for (int tN = 0; tN < 4; ++tN)
#pragma unroll
        for (int f = 0; f < 2; ++f)
#pragma unroll
            for (int j = 0; j < 8; ++j) {
                int k = 32*f + 8*q4 + j, n = 16*tN + ln15;
                AfZ[tN][f][j] = (_Float16)zW2[k*64 + n];
                AfQ[tN][f][j] = (_Float16)qW2[k*64 + n];
            }

    // ---- layer-2 bias along Dt rows: row n = 16tN + 4q4 + r ----
    f32x4 b2zv[4], b2qv[4];
#pragma unroll
    for (int tN = 0; tN < 4; ++tN)
#pragma unroll
        for (int r = 0; r < 4; ++r) {
            b2zv[tN][r] = zb2[16*tN + 4*q4 + r];
            b2qv[tN][r] = qb2[16*tN + 4*q4 + r];
        }

    // ---- layer-3 combined A-frags for 16x16x32 (z prescaled by SQRTDT) ----
    const int c3 = ln15 & 3;
    f16x8 A3[4];
#pragma unroll
    for (int f = 0; f < 4; ++f)
#pragma unroll
        for (int j = 0; j < 8; ++j) {
            int tN = 2*(f & 1) + (j >> 2);
            int n  = 16*tN + 4*q4 + (j & 3);
            float wv = (f < 2) ? ((c3 < 3)  ? SQRTDT * zW3[n*3 + c3] : 0.0f)
                               : ((c3 == 3) ? qW3[n]                 : 0.0f);
            A3[f][j] = (_Float16)wv;
        }

    float y = y0[0], Yv = Y0[0], acc = 0.0f;
    const float CSIG = SIGMA0_ * SQRTDT;       // diffusion coefficient
    const float NHDT = -0.5f * DT_;            // -f*dt factor
    const f32x4 C3bias = {SQRTDT * zb3[0], SQRTDT * zb3[1], SQRTDT * zb3[2], qb3[0]};

    const f16x2 zero2h = {(_Float16)0.0f, (_Float16)0.0f};
    const f16x4 zero4h = {(_Float16)0.0f, (_Float16)0.0f, (_Float16)0.0f, (_Float16)0.0f};
    const f32x4 zero4  = {0.0f, 0.0f, 0.0f, 0.0f};

    // cur/nxt ping-pong registers for the t-table (4 x f16x8 each)
    f16x8 cz0, cz1, cq0, cq1, dz0, dz1, dq0, dq1;

    auto body = [&](int i,
                    f16x8& tz0, f16x8& tz1, f16x8& tq0, f16x8& tq1,
                    f16x8& uz0, f16x8& uz1, f16x8& uq0, f16x8& uq1) {
        const float* sl = (const float*)&ring[w][i & 7][0];
        float nw0 = sl[ln15*3 + 0], nw1 = sl[ln15*3 + 1], nw2 = sl[ln15*3 + 2];
        float nz0 = sl[48 + ln15*3 + 0], nz1 = sl[48 + ln15*3 + 1], nz2 = sl[48 + ln15*3 + 2];

        // prefetch next step's t-table slice (consumed next body call)
        int ip = i + 1; ip = (ip > NSTEPS - 1) ? NSTEPS - 1 : ip;
        {
            const f16x8* tp = (const f16x8*)(tbl + (ip*4 + q4)*32);
            uz0 = tp[0]; uz1 = tp[1]; uq0 = tp[2]; uq1 = tp[3];
        }

        // ---- h1: max(B1*y + T, 0) in packed f16; pairs ARE the B-frag ----
        _Float16 yh = (_Float16)y;
        const f16x2 yv = {yh, yh};
        union U8 { f16x8 v; f16x2 h[4]; };
        U8 Tz0; Tz0.v = tz0; U8 Tz1; Tz1.v = tz1;
        U8 Tq0; Tq0.v = tq0; U8 Tq1; Tq1.v = tq1;
        union { f16x2 h[4]; f16x8 v; } bz0, bz1, bq0, bq1;
#pragma unroll
        for (int m = 0; m < 4; ++m) {
            bz0.h[m] = __builtin_elementwise_max((f16x2)(B1z[m]*yv + Tz0.h[m]), zero2h);
            bq0.h[m] = __builtin_elementwise_max((f16x2)(B1q[m]*yv + Tq0.h[m]), zero2h);
            bz1.h[m] = __builtin_elementwise_max((f16x2)(B1z[m+4]*yv + Tz1.h[m]), zero2h);
            bq1.h[m] = __builtin_elementwise_max((f16x2)(B1q[m+4]*yv + Tq1.h[m]), zero2h);
        }

        // ---- layer-2: f16 MFMA, Dt[n][path]; pack then packed relu ----
        union { f16x4 q[4]; f16x8 o[2]; } Bz, Bq;
#pragma unroll
        for (int tN = 0; tN < 4; ++tN) {
            f32x4 dz = b2zv[tN];
            dz = __builtin_amdgcn_mfma_f32_16x16x32_f16(AfZ[tN][0], bz0.v, dz, 0, 0, 0);
            dz = __builtin_amdgcn_mfma_f32_16x16x32_f16(AfZ[tN][1], bz1.v, dz, 0, 0, 0);
            f32x4 dq = b2qv[tN];
            dq = __builtin_amdgcn_mfma_f32_16x16x32_f16(AfQ[tN][0], bq0.v, dq, 0, 0, 0);
            dq = __builtin_amdgcn_mfma_f32_16x16x32_f16(AfQ[tN][1], bq1.v, dq, 0, 0, 0);
            Bz.q[tN] = __builtin_elementwise_max(pk4(dz), zero4h);
            Bq.q[tN] = __builtin_elementwise_max(pk4(dq), zero4h);
        }

        // ---- layer-3: biases ride the z-chain C-input; P = (z0s,z1s,z2s,q) ----
        f32x4 Pz = C3bias, Pq = zero4;
        Pz = __builtin_amdgcn_mfma_f32_16x16x32_f16(A3[0], Bz.o[0], Pz, 0, 0, 0);
        Pz = __builtin_amdgcn_mfma_f32_16x16x32_f16(A3[1], Bz.o[1], Pz, 0, 0, 0);
        Pq = __builtin_amdgcn_mfma_f32_16x16x32_f16(A3[2], Bq.o[0], Pq, 0, 0, 0);
        Pq = __builtin_amdgcn_mfma_f32_16x16x32_f16(A3[3], Bq.o[1], Pq, 0, 0, 0);
        f32x4 P = Pz + Pq;

        // ---- scalar epilogue (z pre-scaled by SQRTDT, biases already in P) ----
        float zs0 = P[0], zs1 = P[1], zs2 = P[2], qv = P[3];
        float zdw = fmaf(zs2, nw2, fmaf(zs1, nw1, zs0*nw0));
        float zdz = fmaf(zs2, nz2, fmaf(zs1, nz1, zs0*nz0));
        float snw = (nw0 + nw1) + nw2;
        Yv = fmaf(NHDT*qv, qv, Yv) + zdw;
        float r = zdw - zdz;                       // residual: (Y - f*DT) cancels
        acc = fmaf(r, r, acc);
        y = fmaf(CSIG, snw, fmaf(qv, DT_, y));
    };

    __syncthreads();                               // table visible to all waves
    {   // step-0 table slice
        const f16x8* tp0 = (const f16x8*)(tbl + q4*32);
        cz0 = tp0[0]; cz1 = tp0[1]; cq0 = tp0[2]; cq1 = tp0[3];
    }

#pragma unroll 1
    for (int i = 0; i < NSTEPS - 4; i += 2) {
        __builtin_amdgcn_s_waitcnt(0x0F73);   // vmcnt(3): slot i complete
        fill(i + 4);
        body(i,     cz0, cz1, cq0, cq1, dz0, dz1, dq0, dq1);
        __builtin_amdgcn_s_waitcnt(0x0F73);   // vmcnt(3): slot i+1 complete
        fill(i + 5);
        body(i + 1, dz0, dz1, dq0, dq1, cz0, cz1, cq0, cq1);
    }
    __builtin_amdgcn_s_waitcnt(0x0F70);       // vmcnt(0): drain remaining fills
    body(NSTEPS - 4, cz0, cz1, cq0, cq1, dz0, dz1, dq0, dq1);
    body(NSTEPS - 3, dz0, dz1, dq0, dq1, cz0, cz1, cq0, cq1);
    body(NSTEPS - 2, cz0, cz1, cq0, cq1, dz0, dz1, dq0, dq1);
    body(NSTEPS - 1, dz0, dz1, dq0, dq1, cz0, cz1, cq0, cq1);

    float dterm = Yv - y*y;
    acc = fmaf(dterm, dterm, acc);

    // q4-replicas hold identical acc -> count q4==0 lanes only
    float val = (q4 == 0) ? acc : 0.0f;
#pragma unroll
    for (int off = 1; off < 64; off <<= 1) val += __shfl_xor(val, off);
    if (lane == 0) atomicAdd(out, val * (1.0f / BATCH));
}

extern "C" void kernel_launch(void* const* d_in, const int* in_sizes, int n_in,
                              void* d_out, int out_size, void* d_ws, size_t ws_size,
                              hipStream_t stream)
{
    zero_out_kernel<<<1, 64, 0, stream>>>((float*)d_out);
    deepbsde_kernel<<<256, 256, 0, stream>>>(
        (const float*)d_in[0],  (const float*)d_in[1],
        (const float*)d_in[2],  (const float*)d_in[3],
        (const float*)d_in[4],  (const float*)d_in[5],
        (const float*)d_in[6],  (const float*)d_in[7],
        (const float*)d_in[8],  (const float*)d_in[9],
        (const float*)d_in[10], (const float*)d_in[11],
        (const float*)d_in[12], (const float*)d_in[13],
        (const float*)d_in[14], (const float*)d_in[15],
        (float*)d_out);
}